// Round 1
// baseline (409.840 us; speedup 1.0000x reference)
//
#include <hip/hip_runtime.h>
#include <math.h>

#define B_ 16
#define C_ 64
#define HW_ 4096          // 64*64
#define PHW_ 1024         // pooled 32*32

// ---------------------------------------------------------------------------
// Kernel 1: fused 1x1 convs (theta/phi/g) + 2x2 maxpool of phi/g.
// 1 thread per pixel. 256 WGs x 256 threads. Weights staged in LDS
// (uniform-index -> broadcast reads, conflict free).
// ---------------------------------------------------------------------------
__global__ __launch_bounds__(256) void conv_stage(
    const float* __restrict__ x,
    const float* __restrict__ Wt,   // [8][64]
    const float* __restrict__ Wp,   // [8][64]
    const float* __restrict__ Wg,   // [32][64]
    float* __restrict__ theta,      // [B][8][HW]
    float* __restrict__ phi_p,      // [B][8][PHW]
    float* __restrict__ g_p)        // [B][32][PHW]
{
    __shared__ float w[64][48];       // [c][ch]  ch 0..8 theta, 8..16 phi, 16..48 g
    __shared__ float pool[256][41];   // 40 used; stride 41 dodges bank conflicts

    const int t = threadIdx.x;

    // stage weights: 3072 elems, 12 per thread
    for (int i = t; i < 64 * 48; i += 256) {
        int c = i / 48, ch = i % 48;
        float v;
        if (ch < 8)       v = Wt[ch * 64 + c];
        else if (ch < 16) v = Wp[(ch - 8) * 64 + c];
        else              v = Wg[(ch - 16) * 64 + c];
        w[c][ch] = v;
    }
    __syncthreads();

    const int gidx = blockIdx.x * 256 + t;
    const int b  = gidx >> 12;       // /4096
    const int hw = gidx & 4095;

    float acc[48];
#pragma unroll
    for (int ch = 0; ch < 48; ch++) acc[ch] = 0.f;

    const float* xp = x + (size_t)b * C_ * HW_ + hw;
    for (int c = 0; c < 64; c++) {
        float xv = xp[(size_t)c * HW_];
#pragma unroll
        for (int ch = 0; ch < 48; ch += 4) {
            float4 wv = *(const float4*)&w[c][ch];
            acc[ch + 0] += wv.x * xv;
            acc[ch + 1] += wv.y * xv;
            acc[ch + 2] += wv.z * xv;
            acc[ch + 3] += wv.w * xv;
        }
    }

    // write theta (full resolution), coalesced per channel
    float* tp = theta + (size_t)b * 8 * HW_ + hw;
#pragma unroll
    for (int o = 0; o < 8; o++) tp[(size_t)o * HW_] = acc[o];

    // 2x2 maxpool of phi/g via LDS
#pragma unroll
    for (int ch = 0; ch < 40; ch++) pool[t][ch] = acc[8 + ch];
    __syncthreads();

    if (t < 64) {
        const int pr = t >> 5;          // 0..1 (pooled row within block)
        const int pc = t & 31;          // 0..31 (pooled col)
        const int l0 = pr * 128 + pc * 2;   // local pixel idx of top-left
        const int blk = blockIdx.x & 15;    // block-within-batch (16 blocks/batch)
        const int p = ((blk * 2 + pr) << 5) + pc;   // global pooled index

        float* pp = phi_p + (size_t)b * 8 * PHW_ + p;
        float* gp = g_p + (size_t)b * 32 * PHW_ + p;
#pragma unroll
        for (int ch = 0; ch < 40; ch++) {
            float m = fmaxf(fmaxf(pool[l0][ch], pool[l0 + 1][ch]),
                            fmaxf(pool[l0 + 64][ch], pool[l0 + 65][ch]));
            if (ch < 8) pp[(size_t)ch * PHW_] = m;
            else        gp[(size_t)(ch - 8) * PHW_] = m;
        }
    }
}

// ---------------------------------------------------------------------------
// Kernel 2: fused attention. 1 thread per query, K chunked through LDS.
// scores are tiny (|s| < ~10) so softmax without max-subtraction is safe and
// makes the accumulation a pure running sum. Epilogue fuses the final 1x1
// conv (W_attn) and the residual add.
// ---------------------------------------------------------------------------
__global__ __launch_bounds__(256) void attn_stage(
    const float* __restrict__ theta_g,  // [B][8][HW]
    const float* __restrict__ phi_g,    // [B][8][PHW]
    const float* __restrict__ g_g,      // [B][32][PHW]
    const float* __restrict__ Wa,       // [64][32]
    const float* __restrict__ x,        // [B][64][HW]
    const float* __restrict__ sigma,    // [1]
    float* __restrict__ out)            // [B][64][HW]
{
    __shared__ float sphi[8][256];
    __shared__ float sg[32][256];
    __shared__ float swa[64 * 32];

    const int t = threadIdx.x;
    const int b = blockIdx.x >> 4;
    const int q = ((blockIdx.x & 15) << 8) + t;

    for (int i = t; i < 2048; i += 256) swa[i] = Wa[i];

    float th[8];
#pragma unroll
    for (int c = 0; c < 8; c++) th[c] = theta_g[((size_t)b * 8 + c) * HW_ + q];

    float acc[32];
#pragma unroll
    for (int c = 0; c < 32; c++) acc[c] = 0.f;
    float lsum = 0.f;

    for (int k0 = 0; k0 < PHW_; k0 += 256) {
        __syncthreads();
#pragma unroll
        for (int c = 0; c < 8; c++)
            sphi[c][t] = phi_g[((size_t)b * 8 + c) * PHW_ + k0 + t];
#pragma unroll
        for (int c = 0; c < 32; c++)
            sg[c][t] = g_g[((size_t)b * 32 + c) * PHW_ + k0 + t];
        __syncthreads();

        for (int k = 0; k < 256; k += 4) {
            float s0 = 0.f, s1 = 0.f, s2 = 0.f, s3 = 0.f;
#pragma unroll
            for (int c = 0; c < 8; c++) {
                float4 pv = *(const float4*)&sphi[c][k];
                s0 += th[c] * pv.x;
                s1 += th[c] * pv.y;
                s2 += th[c] * pv.z;
                s3 += th[c] * pv.w;
            }
            float p0 = __expf(s0), p1 = __expf(s1);
            float p2 = __expf(s2), p3 = __expf(s3);
            lsum += (p0 + p1) + (p2 + p3);
#pragma unroll
            for (int c = 0; c < 32; c++) {
                float4 gv = *(const float4*)&sg[c][k];
                acc[c] += p0 * gv.x + p1 * gv.y + p2 * gv.z + p3 * gv.w;
            }
        }
    }

    const float inv = 1.f / lsum;
    const float sig = sigma[0];
#pragma unroll
    for (int c = 0; c < 32; c++) acc[c] *= inv;

    const float* xb = x + (size_t)b * C_ * HW_ + q;
    float* ob = out + (size_t)b * C_ * HW_ + q;
    for (int o = 0; o < 64; o++) {
        float v = 0.f;
#pragma unroll
        for (int c = 0; c < 32; c += 4) {
            float4 wv = *(const float4*)&swa[o * 32 + c];
            v += wv.x * acc[c] + wv.y * acc[c + 1] + wv.z * acc[c + 2] + wv.w * acc[c + 3];
        }
        ob[(size_t)o * HW_] = xb[(size_t)o * HW_] + sig * v;
    }
}

// ---------------------------------------------------------------------------
extern "C" void kernel_launch(void* const* d_in, const int* in_sizes, int n_in,
                              void* d_out, int out_size, void* d_ws, size_t ws_size,
                              hipStream_t stream) {
    const float* x     = (const float*)d_in[0];
    const float* Wt    = (const float*)d_in[1];
    const float* Wp    = (const float*)d_in[2];
    const float* Wg    = (const float*)d_in[3];
    const float* Wa    = (const float*)d_in[4];
    const float* sigma = (const float*)d_in[5];
    float* out = (float*)d_out;

    // workspace layout (floats)
    float* ws    = (float*)d_ws;
    float* theta = ws;                                   // B*8*HW   = 524288
    float* phi_p = theta + (size_t)B_ * 8 * HW_;         // B*8*PHW  = 131072
    float* g_p   = phi_p + (size_t)B_ * 8 * PHW_;        // B*32*PHW = 524288

    conv_stage<<<256, 256, 0, stream>>>(x, Wt, Wp, Wg, theta, phi_p, g_p);
    attn_stage<<<256, 256, 0, stream>>>(theta, phi_p, g_p, Wa, x, sigma, out);
}

// Round 2
// 244.418 us; speedup vs baseline: 1.6768x; 1.6768x over previous
//
#include <hip/hip_runtime.h>
#include <math.h>

#define B_ 16
#define C_ 64
#define HW_ 4096          // 64*64
#define PHW_ 1024         // pooled 32*32

// ---------------------------------------------------------------------------
// Kernel 1: fused 1x1 convs (theta/phi/g) + 2x2 maxpool of phi/g.
// Grid = 1024 blocks = 256 pixel-chunks x 4 channel-groups (12 ch each) so we
// get 16 waves/CU instead of 4 (the old 256-block grid was 1 wave/SIMD and
// latency-bound at 36% VALUBusy). Weights in LDS (broadcast reads).
// ---------------------------------------------------------------------------
__global__ __launch_bounds__(256) void conv_stage(
    const float* __restrict__ x,
    const float* __restrict__ Wt,   // [8][64]
    const float* __restrict__ Wp,   // [8][64]
    const float* __restrict__ Wg,   // [32][64]
    float* __restrict__ theta,      // [B][8][HW]
    float* __restrict__ phi_p,      // [B][8][PHW]
    float* __restrict__ g_p)        // [B][32][PHW]
{
    __shared__ float w[64][12];       // [c][j] this group's 12 channels
    __shared__ float pool[256][13];   // stride 13 dodges bank conflicts

    const int t = threadIdx.x;
    const int chunk = blockIdx.x >> 2;   // 0..255 pixel chunk
    const int grp   = blockIdx.x & 3;    // 0..3 channel group
    const int base  = grp * 12;          // global channel base (0..47)

    // stage this group's weights: 768 elems, 3 per thread
    for (int i = t; i < 64 * 12; i += 256) {
        int c = i / 12, j = i % 12;
        int gch = base + j;
        float v;
        if (gch < 8)       v = Wt[gch * 64 + c];
        else if (gch < 16) v = Wp[(gch - 8) * 64 + c];
        else               v = Wg[(gch - 16) * 64 + c];
        w[c][j] = v;
    }
    __syncthreads();

    const int b   = chunk >> 4;      // batch
    const int blk = chunk & 15;      // 4-row band within image
    const int hw  = blk * 256 + t;   // pixel index

    float acc[12];
#pragma unroll
    for (int j = 0; j < 12; j++) acc[j] = 0.f;

    const float* xp = x + (size_t)b * C_ * HW_ + hw;
    for (int c = 0; c < 64; c++) {
        float xv = xp[(size_t)c * HW_];
#pragma unroll
        for (int j = 0; j < 12; j += 4) {
            float4 wv = *(const float4*)&w[c][j];
            acc[j + 0] += wv.x * xv;
            acc[j + 1] += wv.y * xv;
            acc[j + 2] += wv.z * xv;
            acc[j + 3] += wv.w * xv;
        }
    }

    // group 0 owns theta (channels 0..7, full resolution)
    if (grp == 0) {
        float* tp = theta + (size_t)b * 8 * HW_ + hw;
#pragma unroll
        for (int j = 0; j < 8; j++) tp[(size_t)j * HW_] = acc[j];
    }

    // 2x2 maxpool of this group's pooled channels via LDS
#pragma unroll
    for (int j = 0; j < 12; j++) pool[t][j] = acc[j];
    __syncthreads();

    if (t < 64) {
        const int pr = t >> 5;               // pooled row within band (0..1)
        const int pc = t & 31;               // pooled col
        const int l0 = pr * 128 + pc * 2;    // local top-left pixel
        const int p  = ((blk * 2 + pr) << 5) + pc;   // global pooled index

#pragma unroll
        for (int j = 0; j < 12; j++) {
            int gch = base + j;
            if (gch < 8) continue;           // theta: not pooled
            float m = fmaxf(fmaxf(pool[l0][j], pool[l0 + 1][j]),
                            fmaxf(pool[l0 + 64][j], pool[l0 + 65][j]));
            int pch = gch - 8;               // 0..7 phi, 8..39 g
            if (pch < 8) phi_p[((size_t)b * 8 + pch) * PHW_ + p] = m;
            else         g_p[((size_t)b * 32 + (pch - 8)) * PHW_ + p] = m;
        }
    }
}

// ---------------------------------------------------------------------------
// Kernel 2: fused attention, K-split for occupancy.
// Block = 1024 threads = 256 queries x 4 kchunks; grid = 256 (B x 16 qchunks).
// Each thread accumulates un-normalized softmax partials (exp without max-
// subtraction is a pure running sum -> K-partials are additive) over its 256
// keys; partials are combined in LDS; the W_attn epilogue + residual is fused.
// LDS = 49 KB (stage region reused for the combine buffer) -> under 64 KB cap.
// ---------------------------------------------------------------------------
__global__ __launch_bounds__(1024) void attn_stage(
    const float* __restrict__ theta_g,  // [B][8][HW]
    const float* __restrict__ phi_g,    // [B][8][PHW]
    const float* __restrict__ g_g,      // [B][32][PHW]
    const float* __restrict__ Wa,       // [64][32]
    const float* __restrict__ x,        // [B][64][HW]
    const float* __restrict__ sigma,    // [1]
    float* __restrict__ out)            // [B][64][HW]
{
    // manual LDS layout: swa [0,2048) | stage [2048, 2048+10240)
    // stage is reused after the main loop as final_[256][34] (8704 floats)
    __shared__ float smem[2048 + 10240];
    float* swa   = smem;
    float* stage = smem + 2048;   // stage[(kc*40 + c)*64 + j]
    float* final_ = stage;        // final_[tq*34 + c], c=0..31 acc, 32 = lsum

    const int t  = threadIdx.x;
    const int kc = t >> 8;        // 0..3 kchunk
    const int tq = t & 255;       // query within block
    const int b  = blockIdx.x >> 4;
    const int qc = blockIdx.x & 15;
    const int q  = qc * 256 + tq;

    for (int i = t; i < 2048; i += 1024) swa[i] = Wa[i];

    float th[8];
#pragma unroll
    for (int c = 0; c < 8; c++) th[c] = theta_g[((size_t)b * 8 + c) * HW_ + q];

    float acc[32];
#pragma unroll
    for (int c = 0; c < 32; c++) acc[c] = 0.f;
    float lsum = 0.f;

    // main loop: this thread's 256 keys, staged 64 at a time
    for (int s = 0; s < 4; s++) {
        const int kbase = kc * 256 + s * 64;
        __syncthreads();
        // each kc-group stages its 40x64 tile (phi 8 + g 32), coalesced
        for (int i = tq; i < 2560; i += 256) {
            int c = i >> 6, j = i & 63;
            float v = (c < 8)
                ? phi_g[((size_t)b * 8 + c) * PHW_ + kbase + j]
                : g_g[((size_t)b * 32 + (c - 8)) * PHW_ + kbase + j];
            stage[(kc * 40 + c) * 64 + j] = v;
        }
        __syncthreads();

        const float* sp = &stage[kc * 40 * 64];
        for (int k = 0; k < 64; k += 4) {
            float s0 = 0.f, s1 = 0.f, s2 = 0.f, s3 = 0.f;
#pragma unroll
            for (int c = 0; c < 8; c++) {
                float4 pv = *(const float4*)&sp[c * 64 + k];   // broadcast
                s0 += th[c] * pv.x;
                s1 += th[c] * pv.y;
                s2 += th[c] * pv.z;
                s3 += th[c] * pv.w;
            }
            float p0 = __expf(s0), p1 = __expf(s1);
            float p2 = __expf(s2), p3 = __expf(s3);
            lsum += (p0 + p1) + (p2 + p3);
#pragma unroll
            for (int c = 0; c < 32; c++) {
                float4 gv = *(const float4*)&sp[(8 + c) * 64 + k];   // broadcast
                acc[c] += p0 * gv.x + p1 * gv.y + p2 * gv.z + p3 * gv.w;
            }
        }
    }

    // combine the 4 K-partials per query (round-robin, stride 34 = 2-way free)
    for (int g = 0; g < 4; g++) {
        __syncthreads();
        if (kc == g) {
            if (g == 0) {
#pragma unroll
                for (int c = 0; c < 32; c++) final_[tq * 34 + c] = acc[c];
                final_[tq * 34 + 32] = lsum;
            } else {
#pragma unroll
                for (int c = 0; c < 32; c++) final_[tq * 34 + c] += acc[c];
                final_[tq * 34 + 32] += lsum;
            }
        }
    }
    __syncthreads();

    // epilogue: 1024 threads = 256 queries x 4 o-slices of 16 outputs
    const int tq2 = t & 255;
    const int og  = (t >> 8) * 16;
    const int q2  = qc * 256 + tq2;

    float a2[32];
    const float inv = 1.f / final_[tq2 * 34 + 32];
#pragma unroll
    for (int c = 0; c < 32; c++) a2[c] = final_[tq2 * 34 + c] * inv;

    const float sig = sigma[0];
    const float* xb = x + (size_t)b * C_ * HW_ + q2;
    float* ob = out + (size_t)b * C_ * HW_ + q2;
    for (int o = og; o < og + 16; o++) {
        float v = 0.f;
#pragma unroll
        for (int c = 0; c < 32; c += 4) {
            float4 wv = *(const float4*)&swa[o * 32 + c];   // broadcast
            v += wv.x * a2[c] + wv.y * a2[c + 1] + wv.z * a2[c + 2] + wv.w * a2[c + 3];
        }
        ob[(size_t)o * HW_] = xb[(size_t)o * HW_] + sig * v;
    }
}

// ---------------------------------------------------------------------------
extern "C" void kernel_launch(void* const* d_in, const int* in_sizes, int n_in,
                              void* d_out, int out_size, void* d_ws, size_t ws_size,
                              hipStream_t stream) {
    const float* x     = (const float*)d_in[0];
    const float* Wt    = (const float*)d_in[1];
    const float* Wp    = (const float*)d_in[2];
    const float* Wg    = (const float*)d_in[3];
    const float* Wa    = (const float*)d_in[4];
    const float* sigma = (const float*)d_in[5];
    float* out = (float*)d_out;

    // workspace layout (floats)
    float* ws    = (float*)d_ws;
    float* theta = ws;                                   // B*8*HW   = 524288
    float* phi_p = theta + (size_t)B_ * 8 * HW_;         // B*8*PHW  = 131072
    float* g_p   = phi_p + (size_t)B_ * 8 * PHW_;        // B*32*PHW = 524288

    conv_stage<<<1024, 256, 0, stream>>>(x, Wt, Wp, Wg, theta, phi_p, g_p);
    attn_stage<<<256, 1024, 0, stream>>>(theta, phi_p, g_p, Wa, x, sigma, out);
}

// Round 3
// 203.790 us; speedup vs baseline: 2.0111x; 1.1994x over previous
//
#include <hip/hip_runtime.h>
#include <math.h>

#define B_ 16
#define C_ 64
#define HW_ 4096          // 64*64
#define PHW_ 1024         // pooled 32*32

// ---------------------------------------------------------------------------
// Kernel 1: fused 1x1 convs (theta/phi/g) + 2x2 maxpool, LDS-tiled.
// Block (b, h2) covers image rows 2*h2, 2*h2+1 (= 128 contiguous pixels).
// x tile staged ONCE into LDS (32 KB); all 48 output channels computed from
// LDS (x read exactly once from HBM). Grid 512 x 256 -> 2 blocks/CU.
// ---------------------------------------------------------------------------
__global__ __launch_bounds__(256) void conv_stage(
    const float* __restrict__ x,
    const float* __restrict__ Wt,   // [8][64]
    const float* __restrict__ Wp,   // [8][64]
    const float* __restrict__ Wg,   // [32][64]
    float* __restrict__ theta,      // [B][8][HW]
    float* __restrict__ phi_p,      // [B][8][PHW]
    float* __restrict__ g_p)        // [B][32][PHW]
{
    __shared__ float sx[64][128];   // [c][px] 32 KB
    __shared__ float sw[64][48];    // [c][ch] 12 KB; ch 0-7 theta, 8-15 phi, 16-47 g

    const int t  = threadIdx.x;
    const int b  = blockIdx.x >> 5;
    const int h2 = blockIdx.x & 31;     // pooled row

    // stage weights (3072 floats, broadcast-read later)
    for (int i = t; i < 3072; i += 256) {
        int c = i / 48, ch = i - c * 48;
        float v;
        if (ch < 8)       v = Wt[ch * 64 + c];
        else if (ch < 16) v = Wp[(ch - 8) * 64 + c];
        else              v = Wg[(ch - 16) * 64 + c];
        sw[c][ch] = v;
    }
    // stage x tile: 8192 floats = 2048 float4, coalesced
    const float* xbase = x + (size_t)b * C_ * HW_ + h2 * 128;
    for (int f = t; f < 2048; f += 256) {
        int c = f >> 5, j4 = f & 31;
        *(float4*)&sx[c][j4 * 4] = *(const float4*)&xbase[(size_t)c * HW_ + j4 * 4];
    }
    __syncthreads();

    // phase 1: theta (full res). 256 threads = 128 px x 2 channel-halves.
    {
        const int px  = t & 127;
        const int ch0 = (t >> 7) * 4;
        float a0 = 0.f, a1 = 0.f, a2 = 0.f, a3 = 0.f;
        for (int c = 0; c < 64; c++) {
            float xv = sx[c][px];
            float4 wv = *(const float4*)&sw[c][ch0];   // wave-broadcast
            a0 += wv.x * xv; a1 += wv.y * xv; a2 += wv.z * xv; a3 += wv.w * xv;
        }
        float* tp = theta + (size_t)b * 8 * HW_ + h2 * 128 + px;
        tp[(size_t)(ch0 + 0) * HW_] = a0;
        tp[(size_t)(ch0 + 1) * HW_] = a1;
        tp[(size_t)(ch0 + 2) * HW_] = a2;
        tp[(size_t)(ch0 + 3) * HW_] = a3;
    }

    // phase 2: pooled phi/g. 256 threads = 32 pooled-cols x 8 groups of 5 ch.
    {
        const int p   = t & 31;
        const int grp = t >> 5;          // 0..7 -> channels 8+grp*5 .. +5
        float a[5][4];
#pragma unroll
        for (int j = 0; j < 5; j++)
#pragma unroll
            for (int u = 0; u < 4; u++) a[j][u] = 0.f;

        for (int c = 0; c < 64; c++) {
            float2 xa = *(const float2*)&sx[c][2 * p];        // row 2h2
            float2 xb2 = *(const float2*)&sx[c][64 + 2 * p];  // row 2h2+1
#pragma unroll
            for (int j = 0; j < 5; j++) {
                float wv = sw[c][8 + grp * 5 + j];
                a[j][0] += wv * xa.x;  a[j][1] += wv * xa.y;
                a[j][2] += wv * xb2.x; a[j][3] += wv * xb2.y;
            }
        }
#pragma unroll
        for (int j = 0; j < 5; j++) {
            float m = fmaxf(fmaxf(a[j][0], a[j][1]), fmaxf(a[j][2], a[j][3]));
            int pch = grp * 5 + j;       // 0..39: 0-7 phi, 8-39 g
            int pidx = h2 * 32 + p;
            if (pch < 8) phi_p[((size_t)b * 8 + pch) * PHW_ + pidx] = m;
            else         g_p[((size_t)b * 32 + (pch - 8)) * PHW_ + pidx] = m;
        }
    }
}

// ---------------------------------------------------------------------------
// Kernel 2: fused attention. Block = 512 threads = 64 query-PAIRS x 8 kchunks
// (2 queries/thread halves the LDS-read per FMA). Grid = 512 (B x 32 qchunks
// of 128) -> 2 blocks/CU resident so barrier stalls of one block overlap
// with compute of the other. Un-normalized softmax partials are additive
// across the K-split; combined in LDS; W_attn + residual fused in epilogue.
// ---------------------------------------------------------------------------
__global__ __launch_bounds__(512, 4) void attn_stage(
    const float* __restrict__ theta_g,  // [B][8][HW]
    const float* __restrict__ phi_g,    // [B][8][PHW]
    const float* __restrict__ g_g,      // [B][32][PHW]
    const float* __restrict__ Wa,       // [64][32]
    const float* __restrict__ x,        // [B][64][HW]
    const float* __restrict__ sigma,    // [1]
    float* __restrict__ out)            // [B][64][HW]
{
    // swa [0,2048) | stage [2048, 2048+10240); stage reused as fin[128][35]
    __shared__ float smem[2048 + 10240];
    float* swa   = smem;
    float* stage = smem + 2048;          // stage[(kc*40 + c)*32 + j]
    float* fin   = stage;                // fin[q*35 + c], c 0..31 acc, 32 lsum

    const int t  = threadIdx.x;          // 0..511
    const int qp = t & 63;               // query pair
    const int kc = t >> 6;               // 0..7 k-chunk (128 keys each)
    const int b  = blockIdx.x >> 5;
    const int qc = blockIdx.x & 31;      // 32 q-chunks of 128
    const int q0 = qc * 128 + qp * 2;

    for (int i = t; i < 2048; i += 512) swa[i] = Wa[i];

    float th0[8], th1[8];
#pragma unroll
    for (int c = 0; c < 8; c++) {
        float2 tv = *(const float2*)&theta_g[((size_t)b * 8 + c) * HW_ + q0];
        th0[c] = tv.x; th1[c] = tv.y;
    }

    float acc0[32], acc1[32];
#pragma unroll
    for (int c = 0; c < 32; c++) { acc0[c] = 0.f; acc1[c] = 0.f; }
    float ls0 = 0.f, ls1 = 0.f;

    // 4 stage-iters x 32 keys per kchunk
    for (int s = 0; s < 4; s++) {
        __syncthreads();
        // stage 10240 floats (8 kc x 40 ch x 32 k) as 2560 float4, 5/thread
        for (int f = t; f < 2560; f += 512) {
            int kcs = f / 320;
            int rem = f - kcs * 320;
            int c   = rem >> 3;
            int j4  = rem & 7;
            int kb  = kcs * 128 + s * 32 + j4 * 4;
            const float* src = (c < 8)
                ? &phi_g[((size_t)b * 8 + c) * PHW_ + kb]
                : &g_g[((size_t)b * 32 + (c - 8)) * PHW_ + kb];
            *(float4*)&stage[(kcs * 40 + c) * 32 + j4 * 4] = *(const float4*)src;
        }
        __syncthreads();

        const float* sp = &stage[kc * 40 * 32];
        for (int k = 0; k < 32; k += 4) {
            float s00 = 0.f, s01 = 0.f, s02 = 0.f, s03 = 0.f;
            float s10 = 0.f, s11 = 0.f, s12 = 0.f, s13 = 0.f;
#pragma unroll
            for (int c = 0; c < 8; c++) {
                float4 pv = *(const float4*)&sp[c * 32 + k];   // broadcast
                s00 += th0[c] * pv.x; s01 += th0[c] * pv.y;
                s02 += th0[c] * pv.z; s03 += th0[c] * pv.w;
                s10 += th1[c] * pv.x; s11 += th1[c] * pv.y;
                s12 += th1[c] * pv.z; s13 += th1[c] * pv.w;
            }
            float p00 = __expf(s00), p01 = __expf(s01), p02 = __expf(s02), p03 = __expf(s03);
            float p10 = __expf(s10), p11 = __expf(s11), p12 = __expf(s12), p13 = __expf(s13);
            ls0 += (p00 + p01) + (p02 + p03);
            ls1 += (p10 + p11) + (p12 + p13);
#pragma unroll
            for (int c = 0; c < 32; c++) {
                float4 gv = *(const float4*)&sp[(8 + c) * 32 + k];   // broadcast
                acc0[c] += p00 * gv.x + p01 * gv.y + p02 * gv.z + p03 * gv.w;
                acc1[c] += p10 * gv.x + p11 * gv.y + p12 * gv.z + p13 * gv.w;
            }
        }
    }

    // combine the 8 K-partials per query (sequential rounds; stride 35)
    for (int g = 0; g < 8; g++) {
        __syncthreads();
        if (kc == g) {
            float* f0 = &fin[(qp * 2 + 0) * 35];
            float* f1 = &fin[(qp * 2 + 1) * 35];
            if (g == 0) {
#pragma unroll
                for (int c = 0; c < 32; c++) { f0[c] = acc0[c]; f1[c] = acc1[c]; }
                f0[32] = ls0; f1[32] = ls1;
            } else {
#pragma unroll
                for (int c = 0; c < 32; c++) { f0[c] += acc0[c]; f1[c] += acc1[c]; }
                f0[32] += ls0; f1[32] += ls1;
            }
        }
    }
    __syncthreads();

    // epilogue: 512 threads = 128 q x 4 o-slices of 16 outputs
    const int tq = t & 127;
    const int og = (t >> 7) * 16;
    const int q2 = qc * 128 + tq;

    float a2[32];
    const float inv = 1.f / fin[tq * 35 + 32];
#pragma unroll
    for (int c = 0; c < 32; c++) a2[c] = fin[tq * 35 + c] * inv;

    const float sig = sigma[0];
    const float* xb = x + (size_t)b * C_ * HW_ + q2;
    float* ob = out + (size_t)b * C_ * HW_ + q2;
    for (int o = og; o < og + 16; o++) {
        float v = 0.f;
#pragma unroll
        for (int c = 0; c < 32; c += 4) {
            float4 wv = *(const float4*)&swa[o * 32 + c];   // broadcast
            v += wv.x * a2[c] + wv.y * a2[c + 1] + wv.z * a2[c + 2] + wv.w * a2[c + 3];
        }
        ob[(size_t)o * HW_] = xb[(size_t)o * HW_] + sig * v;
    }
}

// ---------------------------------------------------------------------------
extern "C" void kernel_launch(void* const* d_in, const int* in_sizes, int n_in,
                              void* d_out, int out_size, void* d_ws, size_t ws_size,
                              hipStream_t stream) {
    const float* x     = (const float*)d_in[0];
    const float* Wt    = (const float*)d_in[1];
    const float* Wp    = (const float*)d_in[2];
    const float* Wg    = (const float*)d_in[3];
    const float* Wa    = (const float*)d_in[4];
    const float* sigma = (const float*)d_in[5];
    float* out = (float*)d_out;

    float* ws    = (float*)d_ws;
    float* theta = ws;                                   // B*8*HW
    float* phi_p = theta + (size_t)B_ * 8 * HW_;         // B*8*PHW
    float* g_p   = phi_p + (size_t)B_ * 8 * PHW_;        // B*32*PHW

    conv_stage<<<512, 256, 0, stream>>>(x, Wt, Wp, Wg, theta, phi_p, g_p);
    attn_stage<<<512, 512, 0, stream>>>(theta, phi_p, g_p, Wa, x, sigma, out);
}

// Round 4
// 111.061 us; speedup vs baseline: 3.6902x; 1.8349x over previous
//
#include <hip/hip_runtime.h>
#include <math.h>

#define B_ 16
#define C_ 64
#define HW_ 4096          // 64*64
#define PHW_ 1024         // pooled 32*32

typedef __attribute__((ext_vector_type(8))) short bf8;    // 8 bf16 = 4 VGPR (MFMA A/B)
typedef __attribute__((ext_vector_type(16))) float fv16;  // 16 f32 (MFMA C/D 32x32)

union FU { bf8 v; unsigned u[4]; };

__device__ inline unsigned short f2bf(float f) {          // RNE f32->bf16
    unsigned u = __float_as_uint(f);
    return (unsigned short)((u + 0x7FFFu + ((u >> 16) & 1u)) >> 16);
}
__device__ inline unsigned packbf(float a, float b) {     // two f32 -> packed bf16x2 (RNE)
    return (unsigned)f2bf(a) | ((unsigned)f2bf(b) << 16);
}
__device__ inline unsigned packtr(float a, float b) {     // truncating pack (fast path)
    return (__float_as_uint(a) >> 16) | (__float_as_uint(b) & 0xFFFF0000u);
}

// ---------------------------------------------------------------------------
// Kernel 1: fused 1x1 convs + 2x2 maxpool (VALU, R3 structure) — now emits
// theta [B][8][HW] fp32 plus bf16 MFMA-fragment-packed phi/g:
//   phi_pack[b][kt32(32)][lane(64)][j(8)]: A-frag of phi^T for S^T=phi^T*theta
//       lane<32: phi[c=j][k = kt32*32 + lane]; lane>=32: zeros (c 8..15 pad)
//   g_pack[b][kt16(64)][lane(64)][j(8)]:  A-frag of g for D=g*P^T
//       g[c = lane&31][k = kt16*16 + (lane>>5)*8 + j]
// ---------------------------------------------------------------------------
__global__ __launch_bounds__(256) void conv_stage(
    const float* __restrict__ x,
    const float* __restrict__ Wt,   // [8][64]
    const float* __restrict__ Wp,   // [8][64]
    const float* __restrict__ Wg,   // [32][64]
    float* __restrict__ theta,      // [B][8][HW]
    unsigned short* __restrict__ phi_pack,
    unsigned short* __restrict__ g_pack)
{
    __shared__ float sx[64][128];     // 32 KB
    __shared__ float sw[64][48];      // 12 KB
    __shared__ float pool2[40][33];   // pooled phi/g staging for pack phase

    const int t  = threadIdx.x;
    const int b  = blockIdx.x >> 5;
    const int h2 = blockIdx.x & 31;     // pooled row

    for (int i = t; i < 3072; i += 256) {
        int c = i / 48, ch = i - c * 48;
        float v;
        if (ch < 8)       v = Wt[ch * 64 + c];
        else if (ch < 16) v = Wp[(ch - 8) * 64 + c];
        else              v = Wg[(ch - 16) * 64 + c];
        sw[c][ch] = v;
    }
    const float* xbase = x + (size_t)b * C_ * HW_ + h2 * 128;
    for (int f = t; f < 2048; f += 256) {
        int c = f >> 5, j4 = f & 31;
        *(float4*)&sx[c][j4 * 4] = *(const float4*)&xbase[(size_t)c * HW_ + j4 * 4];
    }
    __syncthreads();

    // phase 1: theta (full res), 128 px x 2 channel-halves
    {
        const int px  = t & 127;
        const int ch0 = (t >> 7) * 4;
        float a0 = 0.f, a1 = 0.f, a2 = 0.f, a3 = 0.f;
        for (int c = 0; c < 64; c++) {
            float xv = sx[c][px];
            float4 wv = *(const float4*)&sw[c][ch0];
            a0 += wv.x * xv; a1 += wv.y * xv; a2 += wv.z * xv; a3 += wv.w * xv;
        }
        float* tp = theta + (size_t)b * 8 * HW_ + h2 * 128 + px;
        tp[(size_t)(ch0 + 0) * HW_] = a0;
        tp[(size_t)(ch0 + 1) * HW_] = a1;
        tp[(size_t)(ch0 + 2) * HW_] = a2;
        tp[(size_t)(ch0 + 3) * HW_] = a3;
    }

    // phase 2: pooled phi/g -> pool2 LDS. 32 pooled-cols x 8 groups of 5 ch.
    {
        const int p   = t & 31;
        const int grp = t >> 5;
        float a[5][4];
#pragma unroll
        for (int j = 0; j < 5; j++)
#pragma unroll
            for (int u = 0; u < 4; u++) a[j][u] = 0.f;

        for (int c = 0; c < 64; c++) {
            float2 xa  = *(const float2*)&sx[c][2 * p];
            float2 xb2 = *(const float2*)&sx[c][64 + 2 * p];
#pragma unroll
            for (int j = 0; j < 5; j++) {
                float wv = sw[c][8 + grp * 5 + j];
                a[j][0] += wv * xa.x;  a[j][1] += wv * xa.y;
                a[j][2] += wv * xb2.x; a[j][3] += wv * xb2.y;
            }
        }
#pragma unroll
        for (int j = 0; j < 5; j++) {
            float m = fmaxf(fmaxf(a[j][0], a[j][1]), fmaxf(a[j][2], a[j][3]));
            pool2[grp * 5 + j][p] = m;   // pch 0-7 phi, 8-39 g
        }
    }
    __syncthreads();

    // pack phase: write bf16 MFMA fragments
    if (t < 64) {
        // phi_pack[b][h2][t][0..7]
        unsigned u0 = 0, u1 = 0, u2 = 0, u3 = 0;
        if (t < 32) {
            float v[8];
#pragma unroll
            for (int j = 0; j < 8; j++) v[j] = pool2[j][t];
            u0 = packbf(v[0], v[1]); u1 = packbf(v[2], v[3]);
            u2 = packbf(v[4], v[5]); u3 = packbf(v[6], v[7]);
        }
        uint4 pkt = make_uint4(u0, u1, u2, u3);
        *(uint4*)(phi_pack + ((size_t)((b * 32 + h2) * 64 + t)) * 8) = pkt;
    } else if (t < 192) {
        const int tt  = t - 64;
        const int ktl = tt >> 6;         // 0..1 (kt16 within this pooled row)
        const int ln  = tt & 63;
        const int c   = ln & 31;
        const int hh  = ln >> 5;
        float v[8];
#pragma unroll
        for (int j = 0; j < 8; j++) v[j] = pool2[8 + c][ktl * 16 + hh * 8 + j];
        uint4 pkt = make_uint4(packbf(v[0], v[1]), packbf(v[2], v[3]),
                               packbf(v[4], v[5]), packbf(v[6], v[7]));
        *(uint4*)(g_pack + ((size_t)((b * 64 + h2 * 2 + ktl) * 64 + ln)) * 8) = pkt;
    }
}

// ---------------------------------------------------------------------------
// Kernel 2: MFMA flash attention (transposed: q lives in the lane dim).
// Block = 256 thr = 2 q-tiles x 2 k-half waves. Wave: 32 queries x 512 keys.
//   S^T[k][q] = phi^T(A) * theta(B)  -> C-layout col=lane&31=q  [stationary q]
//   P = exp2(S^T)  (theta pre-scaled by log2e); lsum = per-lane running sum
//   P^T C-regs -> PV B-frags via 8x shfl_xor(32) + cndmask (no LDS!)
//   D[c][q] += g(A) * P^T(B);  K-halves combined once via LDS;
//   epilogue: D2[o][q] = Wa(A) * O_norm(B) MFMA + residual, fused store.
// ---------------------------------------------------------------------------
__global__ __launch_bounds__(256, 4) void attn_mfma(
    const float* __restrict__ theta_g,              // [B][8][HW]
    const unsigned short* __restrict__ phi_pack,
    const unsigned short* __restrict__ g_pack,
    const float* __restrict__ Wa,                   // [64][32]
    const float* __restrict__ x,
    const float* __restrict__ sigma,
    float* __restrict__ out)
{
    __shared__ float comb[4][64][17];

    const int t = threadIdx.x, wave = t >> 6, lane = t & 63;
    const int lo = lane & 31, hi = lane >> 5;
    const int qtile = blockIdx.x * 2 + (wave >> 1);
    const int khalf = wave & 1;
    const int b = qtile >> 7, qt = qtile & 127;
    const int qg = qt * 32 + lo;                    // this lane's query column

    // theta B-frag (n=q in lo, kd=c=hi*8+j; hi half = zero pad), x log2e
    FU tb; tb.u[0] = tb.u[1] = tb.u[2] = tb.u[3] = 0;
    if (hi == 0) {
        const float LOG2E = 1.4426950408889634f;
        float tv[8];
#pragma unroll
        for (int j = 0; j < 8; j++)
            tv[j] = theta_g[(((size_t)b * 8 + j) << 12) + qg] * LOG2E;
        tb.u[0] = packbf(tv[0], tv[1]); tb.u[1] = packbf(tv[2], tv[3]);
        tb.u[2] = packbf(tv[4], tv[5]); tb.u[3] = packbf(tv[6], tv[7]);
    }

    fv16 zf, acc;
#pragma unroll
    for (int r = 0; r < 16; r++) { zf[r] = 0.f; acc[r] = 0.f; }
    float ps = 0.f;

    const int kt0 = khalf * 16;
    for (int kt = kt0; kt < kt0 + 16; kt++) {
        FU pa;
        pa.v = *(const bf8*)(phi_pack + ((size_t)((b * 32 + kt) * 64 + lane)) * 8);
        fv16 s = __builtin_amdgcn_mfma_f32_32x32x16_bf16(pa.v, tb.v, zf, 0, 0, 0);

        float p[16];
#pragma unroll
        for (int r = 0; r < 16; r++) { p[r] = __builtin_amdgcn_exp2f(s[r]); ps += p[r]; }

        unsigned pk[8], qk[8];
#pragma unroll
        for (int i = 0; i < 8; i++) pk[i] = packtr(p[2 * i], p[2 * i + 1]);
#pragma unroll
        for (int i = 0; i < 8; i++) qk[i] = (unsigned)__shfl_xor((int)pk[i], 32);

        // P^T B-frags: lane's C-regs hold k-rows {0-3,8-11,16-19,24-27}+4*hi;
        // partner (lane^32) holds the interleaved +4 rows. (derivation checked)
        FU pb0, pb1;
        pb0.u[0] = hi ? qk[2] : pk[0]; pb0.u[1] = hi ? qk[3] : pk[1];
        pb0.u[2] = hi ? pk[2] : qk[0]; pb0.u[3] = hi ? pk[3] : qk[1];
        pb1.u[0] = hi ? qk[6] : pk[4]; pb1.u[1] = hi ? qk[7] : pk[5];
        pb1.u[2] = hi ? pk[6] : qk[4]; pb1.u[3] = hi ? pk[7] : qk[5];

        FU ga0, ga1;
        ga0.v = *(const bf8*)(g_pack + ((size_t)((b * 64 + kt * 2    ) * 64 + lane)) * 8);
        ga1.v = *(const bf8*)(g_pack + ((size_t)((b * 64 + kt * 2 + 1) * 64 + lane)) * 8);
        acc = __builtin_amdgcn_mfma_f32_32x32x16_bf16(ga0.v, pb0.v, acc, 0, 0, 0);
        acc = __builtin_amdgcn_mfma_f32_32x32x16_bf16(ga1.v, pb1.v, acc, 0, 0, 0);
    }

    // combine the two K-halves (waves w and w^1 share a q-tile)
#pragma unroll
    for (int r = 0; r < 16; r++) comb[wave][lane][r] = acc[r];
    comb[wave][lane][16] = ps;
    __syncthreads();
    const int pw = wave ^ 1;
#pragma unroll
    for (int r = 0; r < 16; r++) acc[r] += comb[pw][lane][r];
    ps += comb[pw][lane][16];

    float lsum = ps + __shfl_xor(ps, 32);
    float inv = 1.f / lsum;

    // normalized O^T in C-layout -> epilogue B-frags (same exchange pattern, c as k)
    float on[16];
#pragma unroll
    for (int r = 0; r < 16; r++) on[r] = acc[r] * inv;
    unsigned pk[8], qk[8];
#pragma unroll
    for (int i = 0; i < 8; i++) pk[i] = packtr(on[2 * i], on[2 * i + 1]);
#pragma unroll
    for (int i = 0; i < 8; i++) qk[i] = (unsigned)__shfl_xor((int)pk[i], 32);
    FU ob0, ob1;
    ob0.u[0] = hi ? qk[2] : pk[0]; ob0.u[1] = hi ? qk[3] : pk[1];
    ob0.u[2] = hi ? pk[2] : qk[0]; ob0.u[3] = hi ? pk[3] : qk[1];
    ob1.u[0] = hi ? qk[6] : pk[4]; ob1.u[1] = hi ? qk[7] : pk[5];
    ob1.u[2] = hi ? pk[6] : qk[4]; ob1.u[3] = hi ? pk[7] : qk[5];

    // Wa A-frags for this wave's o-half (mtile = khalf)
    FU wa0, wa1;
    {
        const float* wr = Wa + (khalf * 32 + lo) * 32;
#pragma unroll
        for (int ktw = 0; ktw < 2; ktw++) {
            float w8[8];
#pragma unroll
            for (int j = 0; j < 8; j++) w8[j] = wr[ktw * 16 + hi * 8 + j];
            FU f;
            f.u[0] = packbf(w8[0], w8[1]); f.u[1] = packbf(w8[2], w8[3]);
            f.u[2] = packbf(w8[4], w8[5]); f.u[3] = packbf(w8[6], w8[7]);
            if (ktw == 0) wa0 = f; else wa1 = f;
        }
    }
    fv16 d2 = __builtin_amdgcn_mfma_f32_32x32x16_bf16(wa0.v, ob0.v, zf, 0, 0, 0);
    d2 = __builtin_amdgcn_mfma_f32_32x32x16_bf16(wa1.v, ob1.v, d2, 0, 0, 0);

    const float sig = sigma[0];
#pragma unroll
    for (int r = 0; r < 16; r++) {
        int row = (r & 3) + ((r >> 2) << 3) + (hi << 2);
        int o = khalf * 32 + row;
        size_t idx = (((size_t)b * 64 + o) << 12) + qg;
        out[idx] = x[idx] + sig * d2[r];
    }
}

// ---------------------------------------------------------------------------
extern "C" void kernel_launch(void* const* d_in, const int* in_sizes, int n_in,
                              void* d_out, int out_size, void* d_ws, size_t ws_size,
                              hipStream_t stream) {
    const float* x     = (const float*)d_in[0];
    const float* Wt    = (const float*)d_in[1];
    const float* Wp    = (const float*)d_in[2];
    const float* Wg    = (const float*)d_in[3];
    const float* Wa    = (const float*)d_in[4];
    const float* sigma = (const float*)d_in[5];
    float* out = (float*)d_out;

    // ws layout: theta fp32 (2 MB) | phi_pack bf16 (512 KB) | g_pack bf16 (1 MB)
    float* theta = (float*)d_ws;                                  // 524288 floats
    unsigned short* phi_pack = (unsigned short*)(theta + (size_t)B_ * 8 * HW_);
    unsigned short* g_pack   = phi_pack + (size_t)B_ * 32 * 64 * 8;

    conv_stage<<<512, 256, 0, stream>>>(x, Wt, Wp, Wg, theta, phi_pack, g_pack);
    attn_mfma<<<1024, 256, 0, stream>>>(theta, phi_pack, g_pack, Wa, x, sigma, out);
}

// Round 5
// 108.000 us; speedup vs baseline: 3.7948x; 1.0283x over previous
//
#include <hip/hip_runtime.h>
#include <math.h>

#define B_ 16
#define C_ 64
#define HW_ 4096          // 64*64
#define PHW_ 1024         // pooled 32*32

typedef __attribute__((ext_vector_type(8))) short bf8;    // 8 bf16 = 4 VGPR (MFMA A/B)
typedef __attribute__((ext_vector_type(16))) float fv16;  // 16 f32 (MFMA C/D 32x32)

union FU { bf8 v; unsigned u[4]; };

__device__ inline unsigned short f2bf(float f) {          // RNE f32->bf16
    unsigned u = __float_as_uint(f);
    return (unsigned short)((u + 0x7FFFu + ((u >> 16) & 1u)) >> 16);
}
__device__ inline unsigned packbf(float a, float b) {     // two f32 -> packed bf16x2 (RNE)
    return (unsigned)f2bf(a) | ((unsigned)f2bf(b) << 16);
}
__device__ inline unsigned packtr(float a, float b) {     // truncating pack (fast path)
    return (__float_as_uint(a) >> 16) | (__float_as_uint(b) & 0xFFFF0000u);
}

// ---------------------------------------------------------------------------
// Kernel 1: fused 1x1 convs + 2x2 maxpool. v2: weights via SGPR scalar loads
// (wave-uniform channel group), x tile in LDS read as float2/lane, pooling
// via shfl_xor(32). Inner loop per c: 1 ds_read_b64 + 24 v_fmac (SGPR wt) —
// no per-FMA LDS traffic. Emits theta fp32 + bf16 MFMA-fragment phi/g packs.
// ---------------------------------------------------------------------------
__global__ __launch_bounds__(256) void conv_stage(
    const float* __restrict__ x,
    const float* __restrict__ Wt,   // [8][64]
    const float* __restrict__ Wp,   // [8][64]
    const float* __restrict__ Wg,   // [32][64]
    float* __restrict__ theta,      // [B][8][HW]
    unsigned short* __restrict__ phi_pack,
    unsigned short* __restrict__ g_pack)
{
    __shared__ float sx[64][128];     // 32 KB
    __shared__ float pool2[40][33];   // pooled phi/g for the pack phase

    const int t  = threadIdx.x;
    const int b  = blockIdx.x >> 5;
    const int h2 = blockIdx.x & 31;     // pooled row (covers image rows 2h2, 2h2+1)

    // stage x tile: 2048 float4, coalesced
    const float* xbase = x + (size_t)b * C_ * HW_ + h2 * 128;
    for (int f = t; f < 2048; f += 256) {
        int c = f >> 5, j4 = f & 31;
        *(float4*)&sx[c][j4 * 4] = *(const float4*)&xbase[(size_t)c * HW_ + j4 * 4];
    }
    __syncthreads();

    // wave w owns 12 output channels; lane owns pixel pair (2*lane, 2*lane+1)
    const int wv   = __builtin_amdgcn_readfirstlane(t >> 6);   // SGPR wave id
    const int lane = t & 63;
    const int chbase = wv * 12;

    // SGPR row pointers for this wave's 12 channels
    const float* wrow[12];
#pragma unroll
    for (int j = 0; j < 12; j++) {
        int gch = chbase + j;
        wrow[j] = (gch < 8) ? (Wt + gch * 64)
                : (gch < 16) ? (Wp + (gch - 8) * 64)
                             : (Wg + (gch - 16) * 64);
    }

    float acc[12][2];
#pragma unroll
    for (int j = 0; j < 12; j++) { acc[j][0] = 0.f; acc[j][1] = 0.f; }

    for (int c = 0; c < 64; c++) {
        float2 xv = *(const float2*)&sx[c][2 * lane];
#pragma unroll
        for (int j = 0; j < 12; j++) {
            float w = wrow[j][c];          // s_load, broadcast operand
            acc[j][0] += w * xv.x;
            acc[j][1] += w * xv.y;
        }
    }

    // theta (wave 0, channels 0..7): direct coalesced float2 store
    if (wv == 0) {
        float* tp = theta + (size_t)b * 8 * HW_ + h2 * 128 + 2 * lane;
#pragma unroll
        for (int j = 0; j < 8; j++)
            *(float2*)&tp[(size_t)j * HW_] = make_float2(acc[j][0], acc[j][1]);
    }

    // pooled channels: hmax then cross-row max via shfl_xor(32)
#pragma unroll
    for (int j = 0; j < 12; j++) {
        int gch = chbase + j;
        if (gch >= 8) {
            float hm = fmaxf(acc[j][0], acc[j][1]);
            float pm = fmaxf(hm, __shfl_xor(hm, 32));
            if (lane < 32) pool2[gch - 8][lane] = pm;   // pch 0-7 phi, 8-39 g
        }
    }
    __syncthreads();

    // pack phase: write bf16 MFMA fragments (same layouts as R4)
    if (t < 64) {
        unsigned u0 = 0, u1 = 0, u2 = 0, u3 = 0;
        if (t < 32) {
            float v[8];
#pragma unroll
            for (int j = 0; j < 8; j++) v[j] = pool2[j][t];
            u0 = packbf(v[0], v[1]); u1 = packbf(v[2], v[3]);
            u2 = packbf(v[4], v[5]); u3 = packbf(v[6], v[7]);
        }
        uint4 pkt = make_uint4(u0, u1, u2, u3);
        *(uint4*)(phi_pack + ((size_t)((b * 32 + h2) * 64 + t)) * 8) = pkt;
    } else if (t < 192) {
        const int tt  = t - 64;
        const int ktl = tt >> 6;         // 0..1 (kt16 within this pooled row)
        const int ln  = tt & 63;
        const int c   = ln & 31;
        const int hh  = ln >> 5;
        float v[8];
#pragma unroll
        for (int j = 0; j < 8; j++) v[j] = pool2[8 + c][ktl * 16 + hh * 8 + j];
        uint4 pkt = make_uint4(packbf(v[0], v[1]), packbf(v[2], v[3]),
                               packbf(v[4], v[5]), packbf(v[6], v[7]));
        *(uint4*)(g_pack + ((size_t)((b * 64 + h2 * 2 + ktl) * 64 + ln)) * 8) = pkt;
    }
}

// ---------------------------------------------------------------------------
// Kernel 2: MFMA flash attention (q in the lane dim). v2: S-tile post-
// processing split into two 8-value halves so peak transient registers drop
// from ~48 to ~20 (R4 likely spilled under the 128-VGPR cap); ga loads hoisted
// to the loop top for prefetch; SGPR-based addressing for the pack loads.
// ---------------------------------------------------------------------------
__global__ __launch_bounds__(256, 4) void attn_mfma(
    const float* __restrict__ theta_g,              // [B][8][HW]
    const unsigned short* __restrict__ phi_pack,
    const unsigned short* __restrict__ g_pack,
    const float* __restrict__ Wa,                   // [64][32]
    const float* __restrict__ x,
    const float* __restrict__ sigma,
    float* __restrict__ out)
{
    __shared__ float comb[4][64][17];

    const int t = threadIdx.x, wave = t >> 6, lane = t & 63;
    const int lo = lane & 31, hi = lane >> 5;
    const int qtile = blockIdx.x * 2 + (wave >> 1);
    const int khalf = wave & 1;
    const int b = qtile >> 7, qt = qtile & 127;
    const int qg = qt * 32 + lo;                    // this lane's query column

    // theta B-frag (n=q in lo, k=c=hi*8+j; hi half = zero pad), x log2e
    FU tb; tb.u[0] = tb.u[1] = tb.u[2] = tb.u[3] = 0;
    if (hi == 0) {
        const float LOG2E = 1.4426950408889634f;
        float tv[8];
#pragma unroll
        for (int j = 0; j < 8; j++)
            tv[j] = theta_g[(((size_t)b * 8 + j) << 12) + qg] * LOG2E;
        tb.u[0] = packbf(tv[0], tv[1]); tb.u[1] = packbf(tv[2], tv[3]);
        tb.u[2] = packbf(tv[4], tv[5]); tb.u[3] = packbf(tv[6], tv[7]);
    }

    fv16 zf, acc;
#pragma unroll
    for (int r = 0; r < 16; r++) { zf[r] = 0.f; acc[r] = 0.f; }
    float ps = 0.f;

    const int kt0 = khalf * 16;
    const unsigned short* phip = phi_pack + ((size_t)((b * 32 + kt0) * 64 + lane)) * 8;
    const unsigned short* gp   = g_pack   + ((size_t)((b * 64 + kt0 * 2) * 64 + lane)) * 8;

#pragma unroll 2
    for (int i = 0; i < 16; i++) {
        FU pa, ga0, ga1;
        pa.v  = *(const bf8*)(phip + (size_t)i * 512);
        ga0.v = *(const bf8*)(gp + (size_t)i * 1024);
        ga1.v = *(const bf8*)(gp + (size_t)i * 1024 + 512);
        fv16 s = __builtin_amdgcn_mfma_f32_32x32x16_bf16(pa.v, tb.v, zf, 0, 0, 0);

        // half A: C-regs 0..7 (k rows {0-3,8-11}+4hi) -> PV B-frag for ga0
        {
            unsigned pk[4], qk[4];
#pragma unroll
            for (int u = 0; u < 4; u++) {
                float p0 = __builtin_amdgcn_exp2f(s[2 * u]);
                float p1 = __builtin_amdgcn_exp2f(s[2 * u + 1]);
                ps += p0 + p1;
                pk[u] = packtr(p0, p1);
            }
#pragma unroll
            for (int u = 0; u < 4; u++) qk[u] = (unsigned)__shfl_xor((int)pk[u], 32);
            FU pb;
            pb.u[0] = hi ? qk[2] : pk[0]; pb.u[1] = hi ? qk[3] : pk[1];
            pb.u[2] = hi ? pk[2] : qk[0]; pb.u[3] = hi ? pk[3] : qk[1];
            acc = __builtin_amdgcn_mfma_f32_32x32x16_bf16(ga0.v, pb.v, acc, 0, 0, 0);
        }
        // half B: C-regs 8..15 (k rows {16-19,24-27}+4hi) -> B-frag for ga1
        {
            unsigned pk[4], qk[4];
#pragma unroll
            for (int u = 0; u < 4; u++) {
                float p0 = __builtin_amdgcn_exp2f(s[8 + 2 * u]);
                float p1 = __builtin_amdgcn_exp2f(s[9 + 2 * u]);
                ps += p0 + p1;
                pk[u] = packtr(p0, p1);
            }
#pragma unroll
            for (int u = 0; u < 4; u++) qk[u] = (unsigned)__shfl_xor((int)pk[u], 32);
            FU pb;
            pb.u[0] = hi ? qk[2] : pk[0]; pb.u[1] = hi ? qk[3] : pk[1];
            pb.u[2] = hi ? pk[2] : qk[0]; pb.u[3] = hi ? pk[3] : qk[1];
            acc = __builtin_amdgcn_mfma_f32_32x32x16_bf16(ga1.v, pb.v, acc, 0, 0, 0);
        }
    }

    // combine the two K-halves (waves w and w^1 share a q-tile)
#pragma unroll
    for (int r = 0; r < 16; r++) comb[wave][lane][r] = acc[r];
    comb[wave][lane][16] = ps;
    __syncthreads();
    const int pw = wave ^ 1;
#pragma unroll
    for (int r = 0; r < 16; r++) acc[r] += comb[pw][lane][r];
    ps += comb[pw][lane][16];

    float lsum = ps + __shfl_xor(ps, 32);
    float inv = 1.f / lsum;

    // normalized O^T in C-layout -> epilogue B-frags (same exchange, c as k)
    float on[16];
#pragma unroll
    for (int r = 0; r < 16; r++) on[r] = acc[r] * inv;
    unsigned pk[8], qk[8];
#pragma unroll
    for (int i = 0; i < 8; i++) pk[i] = packtr(on[2 * i], on[2 * i + 1]);
#pragma unroll
    for (int i = 0; i < 8; i++) qk[i] = (unsigned)__shfl_xor((int)pk[i], 32);
    FU ob0, ob1;
    ob0.u[0] = hi ? qk[2] : pk[0]; ob0.u[1] = hi ? qk[3] : pk[1];
    ob0.u[2] = hi ? pk[2] : qk[0]; ob0.u[3] = hi ? pk[3] : qk[1];
    ob1.u[0] = hi ? qk[6] : pk[4]; ob1.u[1] = hi ? qk[7] : pk[5];
    ob1.u[2] = hi ? pk[6] : qk[4]; ob1.u[3] = hi ? pk[7] : qk[5];

    // Wa A-frags for this wave's o-half (mtile = khalf)
    FU wa0, wa1;
    {
        const float* wr = Wa + (khalf * 32 + lo) * 32;
#pragma unroll
        for (int ktw = 0; ktw < 2; ktw++) {
            float w8[8];
#pragma unroll
            for (int j = 0; j < 8; j++) w8[j] = wr[ktw * 16 + hi * 8 + j];
            FU f;
            f.u[0] = packbf(w8[0], w8[1]); f.u[1] = packbf(w8[2], w8[3]);
            f.u[2] = packbf(w8[4], w8[5]); f.u[3] = packbf(w8[6], w8[7]);
            if (ktw == 0) wa0 = f; else wa1 = f;
        }
    }
    fv16 d2 = __builtin_amdgcn_mfma_f32_32x32x16_bf16(wa0.v, ob0.v, zf, 0, 0, 0);
    d2 = __builtin_amdgcn_mfma_f32_32x32x16_bf16(wa1.v, ob1.v, d2, 0, 0, 0);

    const float sig = sigma[0];
#pragma unroll
    for (int r = 0; r < 16; r++) {
        int row = (r & 3) + ((r >> 2) << 3) + (hi << 2);
        int o = khalf * 32 + row;
        size_t idx = (((size_t)b * 64 + o) << 12) + qg;
        out[idx] = x[idx] + sig * d2[r];
    }
}

// ---------------------------------------------------------------------------
extern "C" void kernel_launch(void* const* d_in, const int* in_sizes, int n_in,
                              void* d_out, int out_size, void* d_ws, size_t ws_size,
                              hipStream_t stream) {
    const float* x     = (const float*)d_in[0];
    const float* Wt    = (const float*)d_in[1];
    const float* Wp    = (const float*)d_in[2];
    const float* Wg    = (const float*)d_in[3];
    const float* Wa    = (const float*)d_in[4];
    const float* sigma = (const float*)d_in[5];
    float* out = (float*)d_out;

    // ws layout: theta fp32 (2 MB) | phi_pack bf16 (512 KB) | g_pack bf16 (1 MB)
    float* theta = (float*)d_ws;                                  // 524288 floats
    unsigned short* phi_pack = (unsigned short*)(theta + (size_t)B_ * 8 * HW_);
    unsigned short* g_pack   = phi_pack + (size_t)B_ * 32 * 64 * 8;

    conv_stage<<<512, 256, 0, stream>>>(x, Wt, Wp, Wg, theta, phi_pack, g_pack);
    attn_mfma<<<1024, 256, 0, stream>>>(theta, phi_pack, g_pack, Wa, x, sigma, out);
}